// Round 1
// baseline (346.132 us; speedup 1.0000x reference)
//
#include <hip/hip_runtime.h>

#define B_ 4
#define T_ 4096
#define D_ 1024
#define R_ (B_*T_)
#define CHUNK_ 64
#define NCH_ (T_/CHUNK_)
#define EPS_ 1.1920929e-07f

typedef unsigned short ushort_t;
typedef __attribute__((ext_vector_type(8))) short short8;
typedef __attribute__((ext_vector_type(4))) float f32x4;

__device__ __forceinline__ float silu_f(float v){ return v / (1.0f + __expf(-v)); }

__device__ __forceinline__ ushort_t f2bf(float f){
    unsigned u = __float_as_uint(f);
    unsigned r = u + 0x7fffu + ((u>>16)&1u);
    return (ushort_t)(r>>16);
}
__device__ __forceinline__ float bf2f(ushort_t s){ return __uint_as_float(((unsigned)s)<<16); }

__device__ __forceinline__ f32x4 mfma16(short8 a, short8 b, f32x4 c){
    return __builtin_amdgcn_mfma_f32_16x16x32_bf16(a, b, c, 0, 0, 0);
}

// ---------------- prep: weight cvt (bf16) + scalar setup ----------------
__global__ void prep_k(const float* __restrict__ s0, const float* __restrict__ s1,
                       const float* __restrict__ s2, const float* __restrict__ s3,
                       const float* __restrict__ s4, const float* __restrict__ s5,
                       ushort_t* __restrict__ d0, ushort_t* __restrict__ d1,
                       ushort_t* __restrict__ d2, ushort_t* __restrict__ d3,
                       ushort_t* __restrict__ d4, ushort_t* __restrict__ d5,
                       const float* __restrict__ logA_seq, const float* __restrict__ logdt_seq,
                       const float* __restrict__ logA_dep, const float* __restrict__ logdt_dep,
                       const int* __restrict__ active_k,
                       float* __restrict__ aseq, float* __restrict__ apowC, float* __restrict__ gain){
    int i = blockIdx.x*256 + threadIdx.x;
    if      (i < 65536)   d0[i] = f2bf(s0[i]);
    else if (i < 131072)  d1[i-65536] = f2bf(s1[i-65536]);
    else if (i < 327680)  d2[i-131072] = f2bf(s2[i-131072]);
    else if (i < 393216)  d3[i-327680] = f2bf(s3[i-327680]);
    else if (i < 458752)  d4[i-393216] = f2bf(s4[i-393216]);
    else if (i < 524288)  d5[i-458752] = f2bf(s5[i-458752]);
    else if (i < 524288 + D_){
        int d = i - 524288;
        float K = (float)(*active_k);
        float a = expf(-expf(logA_seq[d]) * expf(logdt_seq[d]));
        a = fmaxf(a, 1e-6f);
        aseq[d] = a;
        apowC[d] = powf(a, (float)CHUNK_);
        float g;
        if (d < 128) {
            g = K;
        } else {
            float ad = expf(-expf(logA_dep[d-128]) * expf(logdt_dep[d-128]));
            float om = 1.0f - ad;
            if (fabsf(om) < 1e-6f) g = K;
            else g = (1.0f - powf(ad, K)) / fmaxf(om, 1e-8f);
        }
        gain[d] = g;
    }
}

// ---------------- rms_norm(x) -> e bf16 ----------------
__global__ __launch_bounds__(256) void rmsbf_k(const float* __restrict__ x, ushort_t* __restrict__ e){
    int row = blockIdx.x;
    int tid = threadIdx.x;
    float4 v = ((const float4*)(x + (size_t)row*D_))[tid];
    float ss = v.x*v.x + v.y*v.y + v.z*v.z + v.w*v.w;
    for (int off=32; off; off>>=1) ss += __shfl_down(ss, off, 64);
    __shared__ float red[4];
    if ((tid&63)==0) red[tid>>6] = ss;
    __syncthreads();
    float tot = red[0]+red[1]+red[2]+red[3];
    float scale = 1.0f / sqrtf(tot*(1.0f/D_) + EPS_);
    ushort4 o;
    o.x = f2bf(v.x*scale); o.y = f2bf(v.y*scale); o.z = f2bf(v.z*scale); o.w = f2bf(v.w*scale);
    ((ushort4*)(e + (size_t)row*D_))[tid] = o;
}

// ---------------- bd2s: drive/hdep blockdiags + fused local chunk scan ----------------
// block = 256 rows x one n-block; each wave owns a 64-row chunk (== CHUNK_)
__global__ __launch_bounds__(256) void bd2s_k(const ushort_t* __restrict__ e,
        const ushort_t* __restrict__ wseq, const ushort_t* __restrict__ wdep,
        const float* __restrict__ gain, const float* __restrict__ aseq,
        ushort_t* __restrict__ hloc, ushort_t* __restrict__ hdep, float* __restrict__ carry){
    __shared__ __align__(16) ushort_t sd[4][64][72];   // drive tiles, wave-private
    __shared__ __align__(16) ushort_t sh[4][16][72];   // hdep tile, wave-private
    int wave = threadIdx.x>>6, lane = threadIdx.x&63;
    int m = lane&15, quad = lane>>4;
    int orow = lane>>2, oq = lane&3;
    int n = blockIdx.y;
    int chunk0 = blockIdx.x*256 + wave*64;

    short8 bs[2][4], bd[2][4];
    #pragma unroll
    for (int s=0;s<2;++s)
        #pragma unroll
        for (int c=0;c<4;++c){
            bs[s][c] = *(const short8*)(wseq + n*4096 + (c*16+m)*64 + s*32 + quad*8);
            bd[s][c] = *(const short8*)(wdep + n*4096 + (c*16+m)*64 + s*32 + quad*8);
        }
    float g[4];
    #pragma unroll
    for (int c=0;c<4;++c) g[c] = gain[n*64 + c*16 + m];

    #pragma unroll
    for (int t=0;t<4;++t){
        int r0 = chunk0 + t*16;
        const ushort_t* ab = e + (size_t)(r0+m)*D_ + n*64 + quad*8;
        short8 a0 = *(const short8*)ab;
        short8 a1 = *(const short8*)(ab + 32);
        f32x4 accs[4], accd[4];
        #pragma unroll
        for (int c=0;c<4;++c){
            accs[c]=(f32x4)0.f; accd[c]=(f32x4)0.f;
            accs[c]=mfma16(a0, bs[0][c], accs[c]);
            accd[c]=mfma16(a0, bd[0][c], accd[c]);
            accs[c]=mfma16(a1, bs[1][c], accs[c]);
            accd[c]=mfma16(a1, bd[1][c], accd[c]);
        }
        #pragma unroll
        for (int c=0;c<4;++c)
            #pragma unroll
            for (int r=0;r<4;++r){
                sd[wave][t*16+quad*4+r][c*16+m] = f2bf(silu_f(accs[c][r]));
                sh[wave][quad*4+r][c*16+m]      = f2bf(g[c]*silu_f(accd[c][r]));
            }
        // hdep store (wave-private LDS -> no barrier needed)
        ushort_t* hb = hdep + (size_t)(r0+orow)*D_ + n*64;
        #pragma unroll
        for (int it=0;it<2;++it)
            *(short8*)(hb + (it*4+oq)*8) = *(const short8*)&sh[wave][orow][(it*4+oq)*8];
    }
    // local serial scan along the wave's 64 rows, one column per lane
    float a = aseq[n*64 + lane];
    float hh = 0.f;
    #pragma unroll 8
    for (int s=0;s<64;++s){
        hh = fmaf(a, hh, bf2f(sd[wave][s][lane]));
        sd[wave][s][lane] = f2bf(hh);
    }
    carry[(size_t)(chunk0>>6)*D_ + n*64 + lane] = hh;
    // store locally-scanned h'
    #pragma unroll
    for (int t=0;t<4;++t){
        ushort_t* db = hloc + (size_t)(chunk0 + t*16 + orow)*D_ + n*64;
        #pragma unroll
        for (int it=0;it<2;++it)
            *(short8*)(db + (it*4+oq)*8) = *(const short8*)&sd[wave][t*16+orow][(it*4+oq)*8];
    }
}

// ---------------- scan2: serial prefix over chunk carries ----------------
__global__ __launch_bounds__(256) void scan2_k(float* __restrict__ carry, const float* __restrict__ apowC){
    int tid = blockIdx.x*256 + threadIdx.x;      // B_*D_ threads
    int d = tid & (D_-1);
    int b = tid >> 10;
    float aC = apowC[d];
    float pref = 0.f;
    for (int c=0;c<NCH_;++c){
        size_t idx = (size_t)(b*NCH_+c)*D_ + d;
        float s = carry[idx];
        carry[idx] = pref;
        pref = fmaf(aC, pref, s);
    }
}

// ---------------- scan3: h = h' + P*a^(s+1) + hdep -> bf16 ----------------
__global__ __launch_bounds__(256) void scan3_k(const ushort_t* __restrict__ hloc,
                                               const ushort_t* __restrict__ hdep,
                                               const float* __restrict__ aseq,
                                               const float* __restrict__ carry,
                                               ushort_t* __restrict__ h){
    int tid = blockIdx.x*256 + threadIdx.x;
    int d  = tid & (D_-1);
    int bc = tid >> 10;
    int c  = bc & (NCH_-1);
    int b  = bc >> 6;
    float a = aseq[d];
    float P = carry[(size_t)bc*D_ + d];
    size_t base = ((size_t)(b*T_ + c*CHUNK_))*D_ + d;
    float apow = a;
    #pragma unroll 4
    for (int s=0; s<CHUNK_; ++s){
        size_t idx = base + (size_t)s*D_;
        h[idx] = f2bf(bf2f(hloc[idx]) + P*apow + bf2f(hdep[idx]));
        apow *= a;
    }
}

// ---------------- hn = h * rsqrt(mean(h^2)+eps), bf16 ----------------
__global__ __launch_bounds__(128) void hn_k(const ushort_t* __restrict__ h, ushort_t* __restrict__ hn){
    int row = blockIdx.x;
    int tid = threadIdx.x;
    short8 v = *(const short8*)(h + (size_t)row*D_ + tid*8);
    float f[8];
    float ss = 0.f;
    #pragma unroll
    for (int j=0;j<8;++j){ f[j] = bf2f((ushort_t)v[j]); ss += f[j]*f[j]; }
    for (int off=32; off; off>>=1) ss += __shfl_down(ss, off, 64);
    __shared__ float red[2];
    if ((tid&63)==0) red[tid>>6] = ss;
    __syncthreads();
    float scale = rsqrtf((red[0]+red[1])*(1.0f/D_) + EPS_);
    short8 o;
    #pragma unroll
    for (int j=0;j<8;++j) o[j] = (short)f2bf(f[j]*scale);
    *(short8*)(hn + (size_t)row*D_ + tid*8) = o;
}

// ---------------- post: r = silu(concat[hn,e,eshift] @ wpost^T) bf16 ----------------
// rows split 2x vs previous version: grid.x = R/128, each wave does 32 rows (t<2)
__global__ __launch_bounds__(256) void post_k(const ushort_t* __restrict__ hn,
                                              const ushort_t* __restrict__ e,
                                              const ushort_t* __restrict__ wpost, ushort_t* __restrict__ rout){
    __shared__ __align__(16) ushort_t st[4][16][72];
    int wave = threadIdx.x>>6, lane = threadIdx.x&63;
    int m = lane&15, quad = lane>>4;
    int orow = lane>>2, oq = lane&3;
    int n = blockIdx.y;

    short8 bw[6][4];
    #pragma unroll
    for (int s=0;s<6;++s)
        #pragma unroll
        for (int c=0;c<4;++c)
            bw[s][c] = *(const short8*)(wpost + n*(64*192) + (c*16+m)*192 + s*32 + quad*8);

    #pragma unroll
    for (int t=0;t<2;++t){
        int r0 = blockIdx.x*128 + wave*32 + t*16;
        int row = r0 + m;
        bool zrow = ((row & (T_-1)) == 0);
        short8 af[6];
        #pragma unroll
        for (int s=0;s<6;++s){
            int g0 = n*192 + s*32;
            if (g0 < 1024){
                af[s] = *(const short8*)(hn + (size_t)row*D_ + g0 + quad*8);
            } else if (g0 < 2048){
                af[s] = *(const short8*)(e + (size_t)row*D_ + (g0-1024) + quad*8);
            } else {
                if (zrow) af[s] = short8{0,0,0,0,0,0,0,0};
                else      af[s] = *(const short8*)(e + (size_t)(row-1)*D_ + (g0-2048) + quad*8);
            }
        }
        f32x4 acc[4];
        #pragma unroll
        for (int c=0;c<4;++c) acc[c]=(f32x4)0.f;
        #pragma unroll
        for (int s=0;s<6;++s)
            #pragma unroll
            for (int c=0;c<4;++c)
                acc[c] = mfma16(af[s], bw[s][c], acc[c]);
        #pragma unroll
        for (int c=0;c<4;++c)
            #pragma unroll
            for (int r=0;r<4;++r)
                st[wave][quad*4+r][c*16+m] = f2bf(silu_f(acc[c][r]));
        ushort_t* db = rout + (size_t)(r0+orow)*D_ + n*64;
        #pragma unroll
        for (int it=0;it<2;++it)
            *(short8*)(db + (it*4+oq)*8) = *(const short8*)&st[wave][orow][(it*4+oq)*8];
    }
}

// ---------------- rlow = r @ lrB^T (K=1024 -> 64) bf16, split-K over 4 waves ----------------
// grid = R/16 blocks; all 4 waves share the same 16 rows, each wave does K=256,
// f32 reduce through LDS. 4x the blocks of the previous version (was 1 block/CU).
__global__ __launch_bounds__(256) void rlow_k(const ushort_t* __restrict__ r, const ushort_t* __restrict__ lrB,
                                              ushort_t* __restrict__ rlow){
    __shared__ __align__(16) float sacc[4][16][68];
    int wave = threadIdx.x>>6, lane = threadIdx.x&63;
    int m = lane&15, quad = lane>>4;
    int r0 = blockIdx.x*16;
    f32x4 acc[4];
    #pragma unroll
    for (int c=0;c<4;++c) acc[c]=(f32x4)0.f;
    const ushort_t* ab = r + (size_t)(r0+m)*D_ + wave*256 + quad*8;
    #pragma unroll
    for (int s=0;s<8;++s){
        short8 a = *(const short8*)(ab + s*32);
        #pragma unroll
        for (int c=0;c<4;++c){
            short8 b = *(const short8*)(lrB + (c*16+m)*1024 + wave*256 + s*32 + quad*8);
            acc[c] = mfma16(a, b, acc[c]);
        }
    }
    #pragma unroll
    for (int c=0;c<4;++c)
        #pragma unroll
        for (int r2=0;r2<4;++r2)
            sacc[wave][quad*4+r2][c*16+m] = acc[c][r2];
    __syncthreads();
    int row  = threadIdx.x>>4;        // 0..15
    int col4 = (threadIdx.x&15)*4;    // 0..60 step 4
    float4 v0 = *(const float4*)&sacc[0][row][col4];
    float4 v1 = *(const float4*)&sacc[1][row][col4];
    float4 v2 = *(const float4*)&sacc[2][row][col4];
    float4 v3 = *(const float4*)&sacc[3][row][col4];
    ushort4 o;
    o.x = f2bf(v0.x+v1.x+v2.x+v3.x);
    o.y = f2bf(v0.y+v1.y+v2.y+v3.y);
    o.z = f2bf(v0.z+v1.z+v2.z+v3.z);
    o.w = f2bf(v0.w+v1.w+v2.w+v3.w);
    *(ushort4*)(rlow + (size_t)(r0+row)*64 + col4) = o;
}

// ---------------- out = x + r@wloc^T + rlow@lrA^T ----------------
// rows split 2x vs previous version: grid.x = R/128, each wave does 32 rows (t<2).
// VGPR=60 previously -> request 8 waves/SIMD so 8 blocks/CU can be resident.
__global__ __launch_bounds__(256, 8) void out_k(const float* __restrict__ x, const ushort_t* __restrict__ r,
        const ushort_t* __restrict__ rlow, const ushort_t* __restrict__ wloc, const ushort_t* __restrict__ lrA,
        float* __restrict__ out){
    __shared__ __align__(16) float st[4][16][68];
    int wave = threadIdx.x>>6, lane = threadIdx.x&63;
    int m = lane&15, quad = lane>>4;
    int orow = lane>>2, oq = lane&3;
    int n = blockIdx.y;

    short8 wl[2][4], la[4][2];
    #pragma unroll
    for (int c=0;c<4;++c)
        #pragma unroll
        for (int s=0;s<2;++s){
            wl[s][c] = *(const short8*)(wloc + n*4096 + (c*16+m)*64 + s*32 + quad*8);
            la[c][s] = *(const short8*)(lrA + (size_t)(n*64 + c*16 + m)*64 + s*32 + quad*8);
        }
    #pragma unroll
    for (int t=0;t<2;++t){
        int r0 = blockIdx.x*128 + wave*32 + t*16;
        const float* xb = x + (size_t)(r0+orow)*D_ + n*64;
        float4 xv[4];
        #pragma unroll
        for (int it=0;it<4;++it) xv[it] = *(const float4*)(xb + (it*4+oq)*4);

        const ushort_t* lb = rlow + (size_t)(r0+m)*64 + quad*8;
        short8 al0 = *(const short8*)lb;
        short8 al1 = *(const short8*)(lb + 32);
        const ushort_t* ab = r + (size_t)(r0+m)*D_ + n*64 + quad*8;
        short8 ar0 = *(const short8*)ab;
        short8 ar1 = *(const short8*)(ab + 32);
        f32x4 acc[4];
        #pragma unroll
        for (int c=0;c<4;++c){
            acc[c]=(f32x4)0.f;
            acc[c]=mfma16(al0, la[c][0], acc[c]);
            acc[c]=mfma16(al1, la[c][1], acc[c]);
            acc[c]=mfma16(ar0, wl[0][c], acc[c]);
            acc[c]=mfma16(ar1, wl[1][c], acc[c]);
        }
        #pragma unroll
        for (int c=0;c<4;++c)
            #pragma unroll
            for (int r2=0;r2<4;++r2)
                st[wave][quad*4+r2][c*16+m] = acc[c][r2];
        float* ob = out + (size_t)(r0+orow)*D_ + n*64;
        #pragma unroll
        for (int it=0;it<4;++it){
            float4 v = *(const float4*)&st[wave][orow][(it*4+oq)*4];
            v.x += xv[it].x; v.y += xv[it].y; v.z += xv[it].z; v.w += xv[it].w;
            *(float4*)(ob + (it*4+oq)*4) = v;
        }
    }
}

extern "C" void kernel_launch(void* const* d_in, const int* in_sizes, int n_in,
                              void* d_out, int out_size, void* d_ws, size_t ws_size,
                              hipStream_t stream) {
    const float* x         = (const float*)d_in[0];
    const int*   active_k  = (const int*)  d_in[1];
    const float* b_seq_w   = (const float*)d_in[2];
    const float* b_depth_w = (const float*)d_in[3];
    const float* w_post_w  = (const float*)d_in[4];
    const float* w_local_w = (const float*)d_in[5];
    const float* lr_A      = (const float*)d_in[6];
    const float* lr_B      = (const float*)d_in[7];
    const float* logA_seq  = (const float*)d_in[8];
    const float* logdt_seq = (const float*)d_in[9];
    const float* logA_dep  = (const float*)d_in[10];
    const float* logdt_dep = (const float*)d_in[11];

    float* ws    = (float*)d_ws;
    float* carry = ws;                               // B_*NCH_*D_ = 262144
    float* aseq  = carry + (size_t)B_*NCH_*D_;
    float* apowC = aseq + D_;
    float* gain  = apowC + D_;
    ushort_t* ub       = (ushort_t*)(gain + D_);
    ushort_t* e_bf     = ub;                         // R_*D_
    ushort_t* hloc_bf  = e_bf + (size_t)R_*D_;       // R_*D_  (h' from bd2s; later reused as hn)
    ushort_t* hdep_bf  = hloc_bf + (size_t)R_*D_;    // R_*D_
    ushort_t* h_bf     = hdep_bf + (size_t)R_*D_;    // R_*D_
    ushort_t* r_bf     = h_bf + (size_t)R_*D_;       // R_*D_
    ushort_t* rlow_bf  = r_bf + (size_t)R_*D_;       // R_*64
    ushort_t* wseq_bf  = rlow_bf + (size_t)R_*64;    // 65536
    ushort_t* wdep_bf  = wseq_bf + 65536;
    ushort_t* wpost_bf = wdep_bf + 65536;            // 196608
    ushort_t* wloc_bf  = wpost_bf + 196608;
    ushort_t* lrA_bf   = wloc_bf + 65536;
    ushort_t* lrB_bf   = lrA_bf + 65536;
    ushort_t* hn_bf    = hloc_bf;                    // alias: hloc dead after scan3

    prep_k<<<(524288 + D_ + 255)/256, 256, 0, stream>>>(
        b_seq_w, b_depth_w, w_post_w, w_local_w, lr_A, lr_B,
        wseq_bf, wdep_bf, wpost_bf, wloc_bf, lrA_bf, lrB_bf,
        logA_seq, logdt_seq, logA_dep, logdt_dep, active_k, aseq, apowC, gain);

    rmsbf_k<<<R_, 256, 0, stream>>>(x, e_bf);
    bd2s_k <<<dim3(R_/256, 16), 256, 0, stream>>>(e_bf, wseq_bf, wdep_bf, gain, aseq,
                                                  hloc_bf, hdep_bf, carry);
    scan2_k<<<(B_*D_)/256, 256, 0, stream>>>(carry, apowC);
    scan3_k<<<(B_*NCH_*D_)/256, 256, 0, stream>>>(hloc_bf, hdep_bf, aseq, carry, h_bf);
    hn_k   <<<R_, 128, 0, stream>>>(h_bf, hn_bf);
    post_k <<<dim3(R_/128, 16), 256, 0, stream>>>(hn_bf, e_bf, wpost_bf, r_bf);
    rlow_k <<<R_/16, 256, 0, stream>>>(r_bf, lrB_bf, rlow_bf);
    out_k  <<<dim3(R_/128, 16), 256, 0, stream>>>(x, r_bf, rlow_bf, wloc_bf, lrA_bf, (float*)d_out);
}

// Round 2
// 308.589 us; speedup vs baseline: 1.1217x; 1.1217x over previous
//
#include <hip/hip_runtime.h>

#define B_ 4
#define T_ 4096
#define D_ 1024
#define R_ (B_*T_)
#define CHUNK_ 64
#define NCH_ (T_/CHUNK_)
#define EPS_ 1.1920929e-07f

typedef unsigned short ushort_t;
typedef __attribute__((ext_vector_type(8))) short short8;
typedef __attribute__((ext_vector_type(4))) float f32x4;

__device__ __forceinline__ float silu_f(float v){ return v / (1.0f + __expf(-v)); }

__device__ __forceinline__ ushort_t f2bf(float f){
    unsigned u = __float_as_uint(f);
    unsigned r = u + 0x7fffu + ((u>>16)&1u);
    return (ushort_t)(r>>16);
}
__device__ __forceinline__ float bf2f(ushort_t s){ return __uint_as_float(((unsigned)s)<<16); }

__device__ __forceinline__ f32x4 mfma16(short8 a, short8 b, f32x4 c){
    return __builtin_amdgcn_mfma_f32_16x16x32_bf16(a, b, c, 0, 0, 0);
}

// ---------------- prep: weight cvt (bf16) + scalar setup ----------------
__global__ void prep_k(const float* __restrict__ s0, const float* __restrict__ s1,
                       const float* __restrict__ s2, const float* __restrict__ s3,
                       const float* __restrict__ s4, const float* __restrict__ s5,
                       ushort_t* __restrict__ d0, ushort_t* __restrict__ d1,
                       ushort_t* __restrict__ d2, ushort_t* __restrict__ d3,
                       ushort_t* __restrict__ d4, ushort_t* __restrict__ d5,
                       const float* __restrict__ logA_seq, const float* __restrict__ logdt_seq,
                       const float* __restrict__ logA_dep, const float* __restrict__ logdt_dep,
                       const int* __restrict__ active_k,
                       float* __restrict__ aseq, float* __restrict__ apowC, float* __restrict__ gain){
    int i = blockIdx.x*256 + threadIdx.x;
    if      (i < 65536)   d0[i] = f2bf(s0[i]);
    else if (i < 131072)  d1[i-65536] = f2bf(s1[i-65536]);
    else if (i < 327680)  d2[i-131072] = f2bf(s2[i-131072]);
    else if (i < 393216)  d3[i-327680] = f2bf(s3[i-327680]);
    else if (i < 458752)  d4[i-393216] = f2bf(s4[i-393216]);
    else if (i < 524288)  d5[i-458752] = f2bf(s5[i-458752]);
    else if (i < 524288 + D_){
        int d = i - 524288;
        float K = (float)(*active_k);
        float a = expf(-expf(logA_seq[d]) * expf(logdt_seq[d]));
        a = fmaxf(a, 1e-6f);
        aseq[d] = a;
        apowC[d] = powf(a, (float)CHUNK_);
        float g;
        if (d < 128) {
            g = K;
        } else {
            float ad = expf(-expf(logA_dep[d-128]) * expf(logdt_dep[d-128]));
            float om = 1.0f - ad;
            if (fabsf(om) < 1e-6f) g = K;
            else g = (1.0f - powf(ad, K)) / fmaxf(om, 1e-8f);
        }
        gain[d] = g;
    }
}

// ---------------- rms_norm(x) -> e bf16 ----------------
__global__ __launch_bounds__(256) void rmsbf_k(const float* __restrict__ x, ushort_t* __restrict__ e){
    int row = blockIdx.x;
    int tid = threadIdx.x;
    float4 v = ((const float4*)(x + (size_t)row*D_))[tid];
    float ss = v.x*v.x + v.y*v.y + v.z*v.z + v.w*v.w;
    for (int off=32; off; off>>=1) ss += __shfl_down(ss, off, 64);
    __shared__ float red[4];
    if ((tid&63)==0) red[tid>>6] = ss;
    __syncthreads();
    float tot = red[0]+red[1]+red[2]+red[3];
    float scale = 1.0f / sqrtf(tot*(1.0f/D_) + EPS_);
    ushort4 o;
    o.x = f2bf(v.x*scale); o.y = f2bf(v.y*scale); o.z = f2bf(v.z*scale); o.w = f2bf(v.w*scale);
    ((ushort4*)(e + (size_t)row*D_))[tid] = o;
}

// ---------------- bd2s: drive/hdep blockdiags + fused local chunk scan ----------------
// block = 256 rows x one n-block; each wave owns a 64-row chunk (== CHUNK_)
__global__ __launch_bounds__(256) void bd2s_k(const ushort_t* __restrict__ e,
        const ushort_t* __restrict__ wseq, const ushort_t* __restrict__ wdep,
        const float* __restrict__ gain, const float* __restrict__ aseq,
        ushort_t* __restrict__ hloc, ushort_t* __restrict__ hdep, float* __restrict__ carry){
    __shared__ __align__(16) ushort_t sd[4][64][72];   // drive tiles, wave-private
    __shared__ __align__(16) ushort_t sh[4][16][72];   // hdep tile, wave-private
    int wave = threadIdx.x>>6, lane = threadIdx.x&63;
    int m = lane&15, quad = lane>>4;
    int orow = lane>>2, oq = lane&3;
    int n = blockIdx.y;
    int chunk0 = blockIdx.x*256 + wave*64;

    short8 bs[2][4], bd[2][4];
    #pragma unroll
    for (int s=0;s<2;++s)
        #pragma unroll
        for (int c=0;c<4;++c){
            bs[s][c] = *(const short8*)(wseq + n*4096 + (c*16+m)*64 + s*32 + quad*8);
            bd[s][c] = *(const short8*)(wdep + n*4096 + (c*16+m)*64 + s*32 + quad*8);
        }
    float g[4];
    #pragma unroll
    for (int c=0;c<4;++c) g[c] = gain[n*64 + c*16 + m];

    #pragma unroll
    for (int t=0;t<4;++t){
        int r0 = chunk0 + t*16;
        const ushort_t* ab = e + (size_t)(r0+m)*D_ + n*64 + quad*8;
        short8 a0 = *(const short8*)ab;
        short8 a1 = *(const short8*)(ab + 32);
        f32x4 accs[4], accd[4];
        #pragma unroll
        for (int c=0;c<4;++c){
            accs[c]=(f32x4)0.f; accd[c]=(f32x4)0.f;
            accs[c]=mfma16(a0, bs[0][c], accs[c]);
            accd[c]=mfma16(a0, bd[0][c], accd[c]);
            accs[c]=mfma16(a1, bs[1][c], accs[c]);
            accd[c]=mfma16(a1, bd[1][c], accd[c]);
        }
        #pragma unroll
        for (int c=0;c<4;++c)
            #pragma unroll
            for (int r=0;r<4;++r){
                sd[wave][t*16+quad*4+r][c*16+m] = f2bf(silu_f(accs[c][r]));
                sh[wave][quad*4+r][c*16+m]      = f2bf(g[c]*silu_f(accd[c][r]));
            }
        // hdep store (wave-private LDS -> no barrier needed)
        ushort_t* hb = hdep + (size_t)(r0+orow)*D_ + n*64;
        #pragma unroll
        for (int it=0;it<2;++it)
            *(short8*)(hb + (it*4+oq)*8) = *(const short8*)&sh[wave][orow][(it*4+oq)*8];
    }
    // local serial scan along the wave's 64 rows, one column per lane
    float a = aseq[n*64 + lane];
    float hh = 0.f;
    #pragma unroll 8
    for (int s=0;s<64;++s){
        hh = fmaf(a, hh, bf2f(sd[wave][s][lane]));
        sd[wave][s][lane] = f2bf(hh);
    }
    carry[(size_t)(chunk0>>6)*D_ + n*64 + lane] = hh;
    // store locally-scanned h'
    #pragma unroll
    for (int t=0;t<4;++t){
        ushort_t* db = hloc + (size_t)(chunk0 + t*16 + orow)*D_ + n*64;
        #pragma unroll
        for (int it=0;it<2;++it)
            *(short8*)(db + (it*4+oq)*8) = *(const short8*)&sd[wave][t*16+orow][(it*4+oq)*8];
    }
}

// ---------------- scan2: serial prefix over chunk carries ----------------
__global__ __launch_bounds__(256) void scan2_k(float* __restrict__ carry, const float* __restrict__ apowC){
    int tid = blockIdx.x*256 + threadIdx.x;      // B_*D_ threads
    int d = tid & (D_-1);
    int b = tid >> 10;
    float aC = apowC[d];
    float pref = 0.f;
    for (int c=0;c<NCH_;++c){
        size_t idx = (size_t)(b*NCH_+c)*D_ + d;
        float s = carry[idx];
        carry[idx] = pref;
        pref = fmaf(aC, pref, s);
    }
}

// ---------------- scan3: h = h' + P*a^(s+1) + hdep -> bf16 ----------------
__global__ __launch_bounds__(256) void scan3_k(const ushort_t* __restrict__ hloc,
                                               const ushort_t* __restrict__ hdep,
                                               const float* __restrict__ aseq,
                                               const float* __restrict__ carry,
                                               ushort_t* __restrict__ h){
    int tid = blockIdx.x*256 + threadIdx.x;
    int d  = tid & (D_-1);
    int bc = tid >> 10;
    int c  = bc & (NCH_-1);
    int b  = bc >> 6;
    float a = aseq[d];
    float P = carry[(size_t)bc*D_ + d];
    size_t base = ((size_t)(b*T_ + c*CHUNK_))*D_ + d;
    float apow = a;
    #pragma unroll 4
    for (int s=0; s<CHUNK_; ++s){
        size_t idx = base + (size_t)s*D_;
        h[idx] = f2bf(bf2f(hloc[idx]) + P*apow + bf2f(hdep[idx]));
        apow *= a;
    }
}

// ---------------- hn = h * rsqrt(mean(h^2)+eps), bf16 ----------------
__global__ __launch_bounds__(128) void hn_k(const ushort_t* __restrict__ h, ushort_t* __restrict__ hn){
    int row = blockIdx.x;
    int tid = threadIdx.x;
    short8 v = *(const short8*)(h + (size_t)row*D_ + tid*8);
    float f[8];
    float ss = 0.f;
    #pragma unroll
    for (int j=0;j<8;++j){ f[j] = bf2f((ushort_t)v[j]); ss += f[j]*f[j]; }
    for (int off=32; off; off>>=1) ss += __shfl_down(ss, off, 64);
    __shared__ float red[2];
    if ((tid&63)==0) red[tid>>6] = ss;
    __syncthreads();
    float scale = rsqrtf((red[0]+red[1])*(1.0f/D_) + EPS_);
    short8 o;
    #pragma unroll
    for (int j=0;j<8;++j) o[j] = (short)f2bf(f[j]*scale);
    *(short8*)(hn + (size_t)row*D_ + tid*8) = o;
}

// ---------------- post: r = silu(concat[hn,e,eshift] @ wpost^T) bf16 ----------------
// rows split 2x: grid.x = R/128, each wave does 32 rows (t<2)
__global__ __launch_bounds__(256) void post_k(const ushort_t* __restrict__ hn,
                                              const ushort_t* __restrict__ e,
                                              const ushort_t* __restrict__ wpost, ushort_t* __restrict__ rout){
    __shared__ __align__(16) ushort_t st[4][16][72];
    int wave = threadIdx.x>>6, lane = threadIdx.x&63;
    int m = lane&15, quad = lane>>4;
    int orow = lane>>2, oq = lane&3;
    int n = blockIdx.y;

    short8 bw[6][4];
    #pragma unroll
    for (int s=0;s<6;++s)
        #pragma unroll
        for (int c=0;c<4;++c)
            bw[s][c] = *(const short8*)(wpost + n*(64*192) + (c*16+m)*192 + s*32 + quad*8);

    #pragma unroll
    for (int t=0;t<2;++t){
        int r0 = blockIdx.x*128 + wave*32 + t*16;
        int row = r0 + m;
        bool zrow = ((row & (T_-1)) == 0);
        short8 af[6];
        #pragma unroll
        for (int s=0;s<6;++s){
            int g0 = n*192 + s*32;
            if (g0 < 1024){
                af[s] = *(const short8*)(hn + (size_t)row*D_ + g0 + quad*8);
            } else if (g0 < 2048){
                af[s] = *(const short8*)(e + (size_t)row*D_ + (g0-1024) + quad*8);
            } else {
                if (zrow) af[s] = short8{0,0,0,0,0,0,0,0};
                else      af[s] = *(const short8*)(e + (size_t)(row-1)*D_ + (g0-2048) + quad*8);
            }
        }
        f32x4 acc[4];
        #pragma unroll
        for (int c=0;c<4;++c) acc[c]=(f32x4)0.f;
        #pragma unroll
        for (int s=0;s<6;++s)
            #pragma unroll
            for (int c=0;c<4;++c)
                acc[c] = mfma16(af[s], bw[s][c], acc[c]);
        #pragma unroll
        for (int c=0;c<4;++c)
            #pragma unroll
            for (int r=0;r<4;++r)
                st[wave][quad*4+r][c*16+m] = f2bf(silu_f(acc[c][r]));
        ushort_t* db = rout + (size_t)(r0+orow)*D_ + n*64;
        #pragma unroll
        for (int it=0;it<2;++it)
            *(short8*)(db + (it*4+oq)*8) = *(const short8*)&st[wave][orow][(it*4+oq)*8];
    }
}

// ---------------- rlow = r @ lrB^T (K=1024 -> 64) bf16, split-K over 4 waves ----------------
// grid = R/16 blocks; all 4 waves share the same 16 rows, each wave does K=256,
// f32 reduce through LDS.
__global__ __launch_bounds__(256) void rlow_k(const ushort_t* __restrict__ r, const ushort_t* __restrict__ lrB,
                                              ushort_t* __restrict__ rlow){
    __shared__ __align__(16) float sacc[4][16][68];
    int wave = threadIdx.x>>6, lane = threadIdx.x&63;
    int m = lane&15, quad = lane>>4;
    int r0 = blockIdx.x*16;
    f32x4 acc[4];
    #pragma unroll
    for (int c=0;c<4;++c) acc[c]=(f32x4)0.f;
    const ushort_t* ab = r + (size_t)(r0+m)*D_ + wave*256 + quad*8;
    #pragma unroll
    for (int s=0;s<8;++s){
        short8 a = *(const short8*)(ab + s*32);
        #pragma unroll
        for (int c=0;c<4;++c){
            short8 b = *(const short8*)(lrB + (c*16+m)*1024 + wave*256 + s*32 + quad*8);
            acc[c] = mfma16(a, b, acc[c]);
        }
    }
    #pragma unroll
    for (int c=0;c<4;++c)
        #pragma unroll
        for (int r2=0;r2<4;++r2)
            sacc[wave][quad*4+r2][c*16+m] = acc[c][r2];
    __syncthreads();
    int row  = threadIdx.x>>4;        // 0..15
    int col4 = (threadIdx.x&15)*4;    // 0..60 step 4
    float4 v0 = *(const float4*)&sacc[0][row][col4];
    float4 v1 = *(const float4*)&sacc[1][row][col4];
    float4 v2 = *(const float4*)&sacc[2][row][col4];
    float4 v3 = *(const float4*)&sacc[3][row][col4];
    ushort4 o;
    o.x = f2bf(v0.x+v1.x+v2.x+v3.x);
    o.y = f2bf(v0.y+v1.y+v2.y+v3.y);
    o.z = f2bf(v0.z+v1.z+v2.z+v3.z);
    o.w = f2bf(v0.w+v1.w+v2.w+v3.w);
    *(ushort4*)(rlow + (size_t)(r0+row)*64 + col4) = o;
}

// ---------------- out = x + r@wloc^T + rlow@lrA^T ----------------
// rows split 2x: grid.x = R/128, each wave does 32 rows (t<2).
// NOTE: no min-waves hint — forcing 8 waves/EU drove VGPR 60->32 and spilled
// (~120 MB extra HBM traffic, dur 53->89 us). VGPR=60 already allows 8 waves/SIMD.
__global__ __launch_bounds__(256) void out_k(const float* __restrict__ x, const ushort_t* __restrict__ r,
        const ushort_t* __restrict__ rlow, const ushort_t* __restrict__ wloc, const ushort_t* __restrict__ lrA,
        float* __restrict__ out){
    __shared__ __align__(16) float st[4][16][68];
    int wave = threadIdx.x>>6, lane = threadIdx.x&63;
    int m = lane&15, quad = lane>>4;
    int orow = lane>>2, oq = lane&3;
    int n = blockIdx.y;

    short8 wl[2][4], la[4][2];
    #pragma unroll
    for (int c=0;c<4;++c)
        #pragma unroll
        for (int s=0;s<2;++s){
            wl[s][c] = *(const short8*)(wloc + n*4096 + (c*16+m)*64 + s*32 + quad*8);
            la[c][s] = *(const short8*)(lrA + (size_t)(n*64 + c*16 + m)*64 + s*32 + quad*8);
        }
    #pragma unroll
    for (int t=0;t<2;++t){
        int r0 = blockIdx.x*128 + wave*32 + t*16;
        const float* xb = x + (size_t)(r0+orow)*D_ + n*64;
        float4 xv[4];
        #pragma unroll
        for (int it=0;it<4;++it) xv[it] = *(const float4*)(xb + (it*4+oq)*4);

        const ushort_t* lb = rlow + (size_t)(r0+m)*64 + quad*8;
        short8 al0 = *(const short8*)lb;
        short8 al1 = *(const short8*)(lb + 32);
        const ushort_t* ab = r + (size_t)(r0+m)*D_ + n*64 + quad*8;
        short8 ar0 = *(const short8*)ab;
        short8 ar1 = *(const short8*)(ab + 32);
        f32x4 acc[4];
        #pragma unroll
        for (int c=0;c<4;++c){
            acc[c]=(f32x4)0.f;
            acc[c]=mfma16(al0, la[c][0], acc[c]);
            acc[c]=mfma16(al1, la[c][1], acc[c]);
            acc[c]=mfma16(ar0, wl[0][c], acc[c]);
            acc[c]=mfma16(ar1, wl[1][c], acc[c]);
        }
        #pragma unroll
        for (int c=0;c<4;++c)
            #pragma unroll
            for (int r2=0;r2<4;++r2)
                st[wave][quad*4+r2][c*16+m] = acc[c][r2];
        float* ob = out + (size_t)(r0+orow)*D_ + n*64;
        #pragma unroll
        for (int it=0;it<4;++it){
            float4 v = *(const float4*)&st[wave][orow][(it*4+oq)*4];
            v.x += xv[it].x; v.y += xv[it].y; v.z += xv[it].z; v.w += xv[it].w;
            *(float4*)(ob + (it*4+oq)*4) = v;
        }
    }
}

extern "C" void kernel_launch(void* const* d_in, const int* in_sizes, int n_in,
                              void* d_out, int out_size, void* d_ws, size_t ws_size,
                              hipStream_t stream) {
    const float* x         = (const float*)d_in[0];
    const int*   active_k  = (const int*)  d_in[1];
    const float* b_seq_w   = (const float*)d_in[2];
    const float* b_depth_w = (const float*)d_in[3];
    const float* w_post_w  = (const float*)d_in[4];
    const float* w_local_w = (const float*)d_in[5];
    const float* lr_A      = (const float*)d_in[6];
    const float* lr_B      = (const float*)d_in[7];
    const float* logA_seq  = (const float*)d_in[8];
    const float* logdt_seq = (const float*)d_in[9];
    const float* logA_dep  = (const float*)d_in[10];
    const float* logdt_dep = (const float*)d_in[11];

    float* ws    = (float*)d_ws;
    float* carry = ws;                               // B_*NCH_*D_ = 262144
    float* aseq  = carry + (size_t)B_*NCH_*D_;
    float* apowC = aseq + D_;
    float* gain  = apowC + D_;
    ushort_t* ub       = (ushort_t*)(gain + D_);
    ushort_t* e_bf     = ub;                         // R_*D_
    ushort_t* hloc_bf  = e_bf + (size_t)R_*D_;       // R_*D_  (h' from bd2s; later reused as hn)
    ushort_t* hdep_bf  = hloc_bf + (size_t)R_*D_;    // R_*D_
    ushort_t* h_bf     = hdep_bf + (size_t)R_*D_;    // R_*D_
    ushort_t* r_bf     = h_bf + (size_t)R_*D_;       // R_*D_
    ushort_t* rlow_bf  = r_bf + (size_t)R_*D_;       // R_*64
    ushort_t* wseq_bf  = rlow_bf + (size_t)R_*64;    // 65536
    ushort_t* wdep_bf  = wseq_bf + 65536;
    ushort_t* wpost_bf = wdep_bf + 65536;            // 196608
    ushort_t* wloc_bf  = wpost_bf + 196608;
    ushort_t* lrA_bf   = wloc_bf + 65536;
    ushort_t* lrB_bf   = lrA_bf + 65536;
    ushort_t* hn_bf    = hloc_bf;                    // alias: hloc dead after scan3

    prep_k<<<(524288 + D_ + 255)/256, 256, 0, stream>>>(
        b_seq_w, b_depth_w, w_post_w, w_local_w, lr_A, lr_B,
        wseq_bf, wdep_bf, wpost_bf, wloc_bf, lrA_bf, lrB_bf,
        logA_seq, logdt_seq, logA_dep, logdt_dep, active_k, aseq, apowC, gain);

    rmsbf_k<<<R_, 256, 0, stream>>>(x, e_bf);
    bd2s_k <<<dim3(R_/256, 16), 256, 0, stream>>>(e_bf, wseq_bf, wdep_bf, gain, aseq,
                                                  hloc_bf, hdep_bf, carry);
    scan2_k<<<(B_*D_)/256, 256, 0, stream>>>(carry, apowC);
    scan3_k<<<(B_*NCH_*D_)/256, 256, 0, stream>>>(hloc_bf, hdep_bf, aseq, carry, h_bf);
    hn_k   <<<R_, 128, 0, stream>>>(h_bf, hn_bf);
    post_k <<<dim3(R_/128, 16), 256, 0, stream>>>(hn_bf, e_bf, wpost_bf, r_bf);
    rlow_k <<<R_/16, 256, 0, stream>>>(r_bf, lrB_bf, rlow_bf);
    out_k  <<<dim3(R_/128, 16), 256, 0, stream>>>(x, r_bf, rlow_bf, wloc_bf, lrA_bf, (float*)d_out);
}

// Round 3
// 285.809 us; speedup vs baseline: 1.2111x; 1.0797x over previous
//
#include <hip/hip_runtime.h>

#define B_ 4
#define T_ 4096
#define D_ 1024
#define R_ (B_*T_)
#define CHUNK_ 64
#define NCH_ (T_/CHUNK_)
#define EPS_ 1.1920929e-07f

typedef unsigned short ushort_t;
typedef __attribute__((ext_vector_type(8))) short short8;
typedef __attribute__((ext_vector_type(4))) float f32x4;

__device__ __forceinline__ float silu_f(float v){ return v / (1.0f + __expf(-v)); }

__device__ __forceinline__ ushort_t f2bf(float f){
    unsigned u = __float_as_uint(f);
    unsigned r = u + 0x7fffu + ((u>>16)&1u);
    return (ushort_t)(r>>16);
}
__device__ __forceinline__ float bf2f(ushort_t s){ return __uint_as_float(((unsigned)s)<<16); }

__device__ __forceinline__ f32x4 mfma16(short8 a, short8 b, f32x4 c){
    return __builtin_amdgcn_mfma_f32_16x16x32_bf16(a, b, c, 0, 0, 0);
}

// ---------------- prep: weight cvt (bf16) + scalar setup ----------------
__global__ void prep_k(const float* __restrict__ s0, const float* __restrict__ s1,
                       const float* __restrict__ s2, const float* __restrict__ s3,
                       const float* __restrict__ s4, const float* __restrict__ s5,
                       ushort_t* __restrict__ d0, ushort_t* __restrict__ d1,
                       ushort_t* __restrict__ d2, ushort_t* __restrict__ d3,
                       ushort_t* __restrict__ d4, ushort_t* __restrict__ d5,
                       const float* __restrict__ logA_seq, const float* __restrict__ logdt_seq,
                       const float* __restrict__ logA_dep, const float* __restrict__ logdt_dep,
                       const int* __restrict__ active_k,
                       float* __restrict__ aseq, float* __restrict__ apowC, float* __restrict__ gain){
    int i = blockIdx.x*256 + threadIdx.x;
    if      (i < 65536)   d0[i] = f2bf(s0[i]);
    else if (i < 131072)  d1[i-65536] = f2bf(s1[i-65536]);
    else if (i < 327680)  d2[i-131072] = f2bf(s2[i-131072]);
    else if (i < 393216)  d3[i-327680] = f2bf(s3[i-327680]);
    else if (i < 458752)  d4[i-393216] = f2bf(s4[i-393216]);
    else if (i < 524288)  d5[i-458752] = f2bf(s5[i-458752]);
    else if (i < 524288 + D_){
        int d = i - 524288;
        float K = (float)(*active_k);
        float a = expf(-expf(logA_seq[d]) * expf(logdt_seq[d]));
        a = fmaxf(a, 1e-6f);
        aseq[d] = a;
        apowC[d] = powf(a, (float)CHUNK_);
        float g;
        if (d < 128) {
            g = K;
        } else {
            float ad = expf(-expf(logA_dep[d-128]) * expf(logdt_dep[d-128]));
            float om = 1.0f - ad;
            if (fabsf(om) < 1e-6f) g = K;
            else g = (1.0f - powf(ad, K)) / fmaxf(om, 1e-8f);
        }
        gain[d] = g;
    }
}

// ---------------- rms_norm(x) -> e bf16 ----------------
__global__ __launch_bounds__(256) void rmsbf_k(const float* __restrict__ x, ushort_t* __restrict__ e){
    int row = blockIdx.x;
    int tid = threadIdx.x;
    float4 v = ((const float4*)(x + (size_t)row*D_))[tid];
    float ss = v.x*v.x + v.y*v.y + v.z*v.z + v.w*v.w;
    for (int off=32; off; off>>=1) ss += __shfl_down(ss, off, 64);
    __shared__ float red[4];
    if ((tid&63)==0) red[tid>>6] = ss;
    __syncthreads();
    float tot = red[0]+red[1]+red[2]+red[3];
    float scale = 1.0f / sqrtf(tot*(1.0f/D_) + EPS_);
    ushort4 o;
    o.x = f2bf(v.x*scale); o.y = f2bf(v.y*scale); o.z = f2bf(v.z*scale); o.w = f2bf(v.w*scale);
    ((ushort4*)(e + (size_t)row*D_))[tid] = o;
}

// ---------------- bd2s: drive/hdep blockdiags + fused local chunk scan ----------------
// block = 256 rows x one n-block; each wave owns a 64-row chunk (== CHUNK_).
// Incremental per-tile scan; writes ONE array hsum = local_scan(drive) + hdep
// (scan3 only ever uses the sum -> saves 32MB write + 32MB read vs separate hdep).
__global__ __launch_bounds__(256) void bd2s_k(const ushort_t* __restrict__ e,
        const ushort_t* __restrict__ wseq, const ushort_t* __restrict__ wdep,
        const float* __restrict__ gain, const float* __restrict__ aseq,
        ushort_t* __restrict__ hsum, float* __restrict__ carry){
    __shared__ __align__(16) ushort_t sd[4][16][72];   // drive tile (then scanned+dep), wave-private
    __shared__ __align__(16) ushort_t sh[4][16][72];   // hdep tile, wave-private
    int wave = threadIdx.x>>6, lane = threadIdx.x&63;
    int m = lane&15, quad = lane>>4;
    int orow = lane>>2, oq = lane&3;
    int n = blockIdx.y;
    int chunk0 = blockIdx.x*256 + wave*64;

    short8 bs[2][4], bd[2][4];
    #pragma unroll
    for (int s=0;s<2;++s)
        #pragma unroll
        for (int c=0;c<4;++c){
            bs[s][c] = *(const short8*)(wseq + n*4096 + (c*16+m)*64 + s*32 + quad*8);
            bd[s][c] = *(const short8*)(wdep + n*4096 + (c*16+m)*64 + s*32 + quad*8);
        }
    float g[4];
    #pragma unroll
    for (int c=0;c<4;++c) g[c] = gain[n*64 + c*16 + m];

    float a = aseq[n*64 + lane];
    float hh = 0.f;

    #pragma unroll
    for (int t=0;t<4;++t){
        int r0 = chunk0 + t*16;
        const ushort_t* ab = e + (size_t)(r0+m)*D_ + n*64 + quad*8;
        short8 a0 = *(const short8*)ab;
        short8 a1 = *(const short8*)(ab + 32);
        f32x4 accs[4], accd[4];
        #pragma unroll
        for (int c=0;c<4;++c){
            accs[c]=(f32x4)0.f; accd[c]=(f32x4)0.f;
            accs[c]=mfma16(a0, bs[0][c], accs[c]);
            accd[c]=mfma16(a0, bd[0][c], accd[c]);
            accs[c]=mfma16(a1, bs[1][c], accs[c]);
            accd[c]=mfma16(a1, bd[1][c], accd[c]);
        }
        #pragma unroll
        for (int c=0;c<4;++c)
            #pragma unroll
            for (int r=0;r<4;++r){
                sd[wave][quad*4+r][c*16+m] = f2bf(silu_f(accs[c][r]));
                sh[wave][quad*4+r][c*16+m] = f2bf(g[c]*silu_f(accd[c][r]));
            }
        // incremental serial scan over this tile's 16 rows (wave-private LDS,
        // in-wave ds ordering -- same pattern as before, no barrier needed)
        #pragma unroll
        for (int s=0;s<16;++s){
            hh = fmaf(a, hh, bf2f(sd[wave][s][lane]));
            sd[wave][s][lane] = f2bf(hh + bf2f(sh[wave][s][lane]));
        }
        // coalesced store of hsum tile
        ushort_t* db = hsum + (size_t)(r0+orow)*D_ + n*64;
        #pragma unroll
        for (int it=0;it<2;++it)
            *(short8*)(db + (it*4+oq)*8) = *(const short8*)&sd[wave][orow][(it*4+oq)*8];
    }
    carry[(size_t)(chunk0>>6)*D_ + n*64 + lane] = hh;
}

// ---------------- scan2: serial prefix over chunk carries ----------------
__global__ __launch_bounds__(256) void scan2_k(float* __restrict__ carry, const float* __restrict__ apowC){
    int tid = blockIdx.x*256 + threadIdx.x;      // B_*D_ threads
    int d = tid & (D_-1);
    int b = tid >> 10;
    float aC = apowC[d];
    float pref = 0.f;
    for (int c=0;c<NCH_;++c){
        size_t idx = (size_t)(b*NCH_+c)*D_ + d;
        float s = carry[idx];
        carry[idx] = pref;
        pref = fmaf(aC, pref, s);
    }
}

// ---------------- scan3: h = hsum + P*a^(s+1) -> bf16 ----------------
__global__ __launch_bounds__(256) void scan3_k(const ushort_t* __restrict__ hsum,
                                               const float* __restrict__ aseq,
                                               const float* __restrict__ carry,
                                               ushort_t* __restrict__ h){
    int tid = blockIdx.x*256 + threadIdx.x;
    int d  = tid & (D_-1);
    int bc = tid >> 10;
    int c  = bc & (NCH_-1);
    int b  = bc >> 6;
    float a = aseq[d];
    float P = carry[(size_t)bc*D_ + d];
    size_t base = ((size_t)(b*T_ + c*CHUNK_))*D_ + d;
    float apow = a;
    #pragma unroll 4
    for (int s=0; s<CHUNK_; ++s){
        size_t idx = base + (size_t)s*D_;
        h[idx] = f2bf(bf2f(hsum[idx]) + P*apow);
        apow *= a;
    }
}

// ---------------- scale[row] = rsqrt(mean(h^2)+eps) ----------------
// replaces the full hn array (was 32MB write + 32MB read); h stays L3-hot.
__global__ __launch_bounds__(256) void scale_k(const ushort_t* __restrict__ h, float* __restrict__ scale){
    int wave = threadIdx.x>>6, lane = threadIdx.x&63;
    int row = blockIdx.x*4 + wave;
    const ushort_t* hb = h + (size_t)row*D_ + lane*16;
    short8 v0 = *(const short8*)hb;
    short8 v1 = *(const short8*)(hb + 8);
    float ss = 0.f;
    #pragma unroll
    for (int j=0;j<8;++j){ float f0 = bf2f((ushort_t)v0[j]); float f1 = bf2f((ushort_t)v1[j]); ss += f0*f0 + f1*f1; }
    for (int off=32; off; off>>=1) ss += __shfl_down(ss, off, 64);
    if (lane==0) scale[row] = rsqrtf(ss*(1.0f/D_) + EPS_);
}

// ---------------- post: r = silu(concat[h*scale,e,eshift] @ wpost^T) bf16 ----------------
// s-loop outermost with unroll-1 so only 4 weight fragments (16 VGPR) are live
// at a time (was 24 fragments = 96 VGPR -> 5 waves/SIMD cap).
__global__ __launch_bounds__(256) void post_k(const ushort_t* __restrict__ h,
                                              const float* __restrict__ scale,
                                              const ushort_t* __restrict__ e,
                                              const ushort_t* __restrict__ wpost, ushort_t* __restrict__ rout){
    __shared__ __align__(16) ushort_t st[4][16][72];
    int wave = threadIdx.x>>6, lane = threadIdx.x&63;
    int m = lane&15, quad = lane>>4;
    int orow = lane>>2, oq = lane&3;
    int n = blockIdx.y;
    int row0 = blockIdx.x*128 + wave*32 + m;

    float scl[2];
    #pragma unroll
    for (int t=0;t<2;++t) scl[t] = (n*192 < 1024) ? scale[row0 + t*16] : 0.f;

    f32x4 acc[2][4];
    #pragma unroll
    for (int t=0;t<2;++t)
        #pragma unroll
        for (int c=0;c<4;++c) acc[t][c]=(f32x4)0.f;

    #pragma unroll 1
    for (int s=0;s<6;++s){
        int g0 = n*192 + s*32;
        short8 bw[4];
        #pragma unroll
        for (int c=0;c<4;++c)
            bw[c] = *(const short8*)(wpost + n*(64*192) + (c*16+m)*192 + s*32 + quad*8);
        #pragma unroll
        for (int t=0;t<2;++t){
            int row = row0 + t*16;
            short8 af;
            if (g0 < 1024){
                short8 hv = *(const short8*)(h + (size_t)row*D_ + g0 + quad*8);
                float sc = scl[t];
                #pragma unroll
                for (int j=0;j<8;++j) af[j] = (short)f2bf(bf2f((ushort_t)hv[j])*sc);
            } else if (g0 < 2048){
                af = *(const short8*)(e + (size_t)row*D_ + (g0-1024) + quad*8);
            } else {
                if ((row & (T_-1)) == 0) af = short8{0,0,0,0,0,0,0,0};
                else af = *(const short8*)(e + (size_t)(row-1)*D_ + (g0-2048) + quad*8);
            }
            #pragma unroll
            for (int c=0;c<4;++c)
                acc[t][c] = mfma16(af, bw[c], acc[t][c]);
        }
    }
    #pragma unroll
    for (int t=0;t<2;++t){
        int r0 = blockIdx.x*128 + wave*32 + t*16;
        #pragma unroll
        for (int c=0;c<4;++c)
            #pragma unroll
            for (int r=0;r<4;++r)
                st[wave][quad*4+r][c*16+m] = f2bf(silu_f(acc[t][c][r]));
        ushort_t* db = rout + (size_t)(r0+orow)*D_ + n*64;
        #pragma unroll
        for (int it=0;it<2;++it)
            *(short8*)(db + (it*4+oq)*8) = *(const short8*)&st[wave][orow][(it*4+oq)*8];
    }
}

// ---------------- rlow = r @ lrB^T (K=1024 -> 64) bf16, split-K over 4 waves ----------------
__global__ __launch_bounds__(256) void rlow_k(const ushort_t* __restrict__ r, const ushort_t* __restrict__ lrB,
                                              ushort_t* __restrict__ rlow){
    __shared__ __align__(16) float sacc[4][16][68];
    int wave = threadIdx.x>>6, lane = threadIdx.x&63;
    int m = lane&15, quad = lane>>4;
    int r0 = blockIdx.x*16;
    f32x4 acc[4];
    #pragma unroll
    for (int c=0;c<4;++c) acc[c]=(f32x4)0.f;
    const ushort_t* ab = r + (size_t)(r0+m)*D_ + wave*256 + quad*8;
    #pragma unroll
    for (int s=0;s<8;++s){
        short8 a = *(const short8*)(ab + s*32);
        #pragma unroll
        for (int c=0;c<4;++c){
            short8 b = *(const short8*)(lrB + (c*16+m)*1024 + wave*256 + s*32 + quad*8);
            acc[c] = mfma16(a, b, acc[c]);
        }
    }
    #pragma unroll
    for (int c=0;c<4;++c)
        #pragma unroll
        for (int r2=0;r2<4;++r2)
            sacc[wave][quad*4+r2][c*16+m] = acc[c][r2];
    __syncthreads();
    int row  = threadIdx.x>>4;        // 0..15
    int col4 = (threadIdx.x&15)*4;    // 0..60 step 4
    float4 v0 = *(const float4*)&sacc[0][row][col4];
    float4 v1 = *(const float4*)&sacc[1][row][col4];
    float4 v2 = *(const float4*)&sacc[2][row][col4];
    float4 v3 = *(const float4*)&sacc[3][row][col4];
    ushort4 o;
    o.x = f2bf(v0.x+v1.x+v2.x+v3.x);
    o.y = f2bf(v0.y+v1.y+v2.y+v3.y);
    o.z = f2bf(v0.z+v1.z+v2.z+v3.z);
    o.w = f2bf(v0.w+v1.w+v2.w+v3.w);
    *(ushort4*)(rlow + (size_t)(r0+row)*64 + col4) = o;
}

// ---------------- out = x + r@wloc^T + rlow@lrA^T ----------------
__global__ __launch_bounds__(256) void out_k(const float* __restrict__ x, const ushort_t* __restrict__ r,
        const ushort_t* __restrict__ rlow, const ushort_t* __restrict__ wloc, const ushort_t* __restrict__ lrA,
        float* __restrict__ out){
    __shared__ __align__(16) float st[4][16][68];
    int wave = threadIdx.x>>6, lane = threadIdx.x&63;
    int m = lane&15, quad = lane>>4;
    int orow = lane>>2, oq = lane&3;
    int n = blockIdx.y;

    short8 wl[2][4], la[4][2];
    #pragma unroll
    for (int c=0;c<4;++c)
        #pragma unroll
        for (int s=0;s<2;++s){
            wl[s][c] = *(const short8*)(wloc + n*4096 + (c*16+m)*64 + s*32 + quad*8);
            la[c][s] = *(const short8*)(lrA + (size_t)(n*64 + c*16 + m)*64 + s*32 + quad*8);
        }
    #pragma unroll
    for (int t=0;t<2;++t){
        int r0 = blockIdx.x*128 + wave*32 + t*16;
        const float* xb = x + (size_t)(r0+orow)*D_ + n*64;
        float4 xv[4];
        #pragma unroll
        for (int it=0;it<4;++it) xv[it] = *(const float4*)(xb + (it*4+oq)*4);

        const ushort_t* lb = rlow + (size_t)(r0+m)*64 + quad*8;
        short8 al0 = *(const short8*)lb;
        short8 al1 = *(const short8*)(lb + 32);
        const ushort_t* ab = r + (size_t)(r0+m)*D_ + n*64 + quad*8;
        short8 ar0 = *(const short8*)ab;
        short8 ar1 = *(const short8*)(ab + 32);
        f32x4 acc[4];
        #pragma unroll
        for (int c=0;c<4;++c){
            acc[c]=(f32x4)0.f;
            acc[c]=mfma16(al0, la[c][0], acc[c]);
            acc[c]=mfma16(al1, la[c][1], acc[c]);
            acc[c]=mfma16(ar0, wl[0][c], acc[c]);
            acc[c]=mfma16(ar1, wl[1][c], acc[c]);
        }
        #pragma unroll
        for (int c=0;c<4;++c)
            #pragma unroll
            for (int r2=0;r2<4;++r2)
                st[wave][quad*4+r2][c*16+m] = acc[c][r2];
        float* ob = out + (size_t)(r0+orow)*D_ + n*64;
        #pragma unroll
        for (int it=0;it<4;++it){
            float4 v = *(const float4*)&st[wave][orow][(it*4+oq)*4];
            v.x += xv[it].x; v.y += xv[it].y; v.z += xv[it].z; v.w += xv[it].w;
            *(float4*)(ob + (it*4+oq)*4) = v;
        }
    }
}

extern "C" void kernel_launch(void* const* d_in, const int* in_sizes, int n_in,
                              void* d_out, int out_size, void* d_ws, size_t ws_size,
                              hipStream_t stream) {
    const float* x         = (const float*)d_in[0];
    const int*   active_k  = (const int*)  d_in[1];
    const float* b_seq_w   = (const float*)d_in[2];
    const float* b_depth_w = (const float*)d_in[3];
    const float* w_post_w  = (const float*)d_in[4];
    const float* w_local_w = (const float*)d_in[5];
    const float* lr_A      = (const float*)d_in[6];
    const float* lr_B      = (const float*)d_in[7];
    const float* logA_seq  = (const float*)d_in[8];
    const float* logdt_seq = (const float*)d_in[9];
    const float* logA_dep  = (const float*)d_in[10];
    const float* logdt_dep = (const float*)d_in[11];

    float* ws    = (float*)d_ws;
    float* carry = ws;                               // B_*NCH_*D_ = 262144
    float* aseq  = carry + (size_t)B_*NCH_*D_;
    float* apowC = aseq + D_;
    float* gain  = apowC + D_;
    float* scale = gain + D_;                        // R_ floats
    ushort_t* ub       = (ushort_t*)(scale + R_);
    ushort_t* e_bf     = ub;                         // R_*D_
    ushort_t* hsum_bf  = e_bf + (size_t)R_*D_;       // R_*D_  (scanned drive + hdep)
    ushort_t* h_bf     = hsum_bf + (size_t)R_*D_;    // R_*D_
    ushort_t* r_bf     = h_bf + (size_t)R_*D_;       // R_*D_
    ushort_t* rlow_bf  = r_bf + (size_t)R_*D_;       // R_*64
    ushort_t* wseq_bf  = rlow_bf + (size_t)R_*64;    // 65536
    ushort_t* wdep_bf  = wseq_bf + 65536;
    ushort_t* wpost_bf = wdep_bf + 65536;            // 196608
    ushort_t* wloc_bf  = wpost_bf + 196608;
    ushort_t* lrA_bf   = wloc_bf + 65536;
    ushort_t* lrB_bf   = lrA_bf + 65536;

    prep_k<<<(524288 + D_ + 255)/256, 256, 0, stream>>>(
        b_seq_w, b_depth_w, w_post_w, w_local_w, lr_A, lr_B,
        wseq_bf, wdep_bf, wpost_bf, wloc_bf, lrA_bf, lrB_bf,
        logA_seq, logdt_seq, logA_dep, logdt_dep, active_k, aseq, apowC, gain);

    rmsbf_k<<<R_, 256, 0, stream>>>(x, e_bf);
    bd2s_k <<<dim3(R_/256, 16), 256, 0, stream>>>(e_bf, wseq_bf, wdep_bf, gain, aseq,
                                                  hsum_bf, carry);
    scan2_k<<<(B_*D_)/256, 256, 0, stream>>>(carry, apowC);
    scan3_k<<<(B_*NCH_*D_)/256, 256, 0, stream>>>(hsum_bf, aseq, carry, h_bf);
    scale_k<<<R_/4, 256, 0, stream>>>(h_bf, scale);
    post_k <<<dim3(R_/128, 16), 256, 0, stream>>>(h_bf, scale, e_bf, wpost_bf, r_bf);
    rlow_k <<<R_/16, 256, 0, stream>>>(r_bf, lrB_bf, rlow_bf);
    out_k  <<<dim3(R_/128, 16), 256, 0, stream>>>(x, r_bf, rlow_bf, wloc_bf, lrA_bf, (float*)d_out);
}